// Round 1
// baseline (419.242 us; speedup 1.0000x reference)
//
#include <hip/hip_runtime.h>
#include <math.h>

#define B_   4096
#define DIN  640
#define DD   128
#define PP   12
#define TM   64
#define BK   32
#define LDA  (TM + 4)   // 68
#define LDB  (DD + 4)   // 132
#define INV_T 0.25f

// ---------------------------------------------------------------------------
// Fused embed: Y = normalize_rows( relu(X @ W1^T + b1) @ W2^T + b2 )
// X: [M, 640], W1: [128, 640], W2: [128, 128], Y: [M, 128]
// Block: 256 threads, computes a 64x128 output tile. Thread microtile 4x8.
// ---------------------------------------------------------------------------
__global__ __launch_bounds__(256) void embed_kernel(
    const float* __restrict__ X, const float* __restrict__ W1,
    const float* __restrict__ bias1, const float* __restrict__ W2,
    const float* __restrict__ bias2, float* __restrict__ Y)
{
  // phase-2 layout: hs[TM][LDB] then Ws[BK][LDB]
  // phase-1 aliases into the hs region: As[BK][LDA] + Bs[BK][LDB] (6400 floats < 8448)
  __shared__ float smem[TM * LDB + BK * LDB];   // 12672 floats = 50688 B
  float* hs = smem;
  float* Ws = smem + TM * LDB;
  float* As = smem;
  float* Bs = smem + BK * LDA;

  const int t  = threadIdx.x;
  const int tx = t & 15;        // col group: cols tx*8 .. tx*8+7
  const int ty = t >> 4;        // row group: rows ty*4 .. ty*4+3
  const long m0 = (long)blockIdx.x * TM;

  float acc[4][8];
#pragma unroll
  for (int i = 0; i < 4; i++)
#pragma unroll
    for (int j = 0; j < 8; j++) acc[i][j] = 0.f;

  // ---- phase 1: h = relu(X @ W1^T + b1) ----
  for (int k0 = 0; k0 < DIN; k0 += BK) {
    // stage A tile (64 rows x 32 k), transposed into As[k][row]
#pragma unroll
    for (int s = 0; s < 2; s++) {
      int f = t + 256 * s;
      int row = f >> 3, kq = f & 7;
      float4 v = *(const float4*)&X[(m0 + row) * DIN + k0 + kq * 4];
      As[(kq * 4 + 0) * LDA + row] = v.x;
      As[(kq * 4 + 1) * LDA + row] = v.y;
      As[(kq * 4 + 2) * LDA + row] = v.z;
      As[(kq * 4 + 3) * LDA + row] = v.w;
    }
    // stage B tile = W1[n][k0..k0+31] transposed into Bs[k][n], n = 0..127
#pragma unroll
    for (int s = 0; s < 4; s++) {
      int f = t + 256 * s;
      int n = f >> 3, kq = f & 7;
      float4 v = *(const float4*)&W1[n * DIN + k0 + kq * 4];
      Bs[(kq * 4 + 0) * LDB + n] = v.x;
      Bs[(kq * 4 + 1) * LDB + n] = v.y;
      Bs[(kq * 4 + 2) * LDB + n] = v.z;
      Bs[(kq * 4 + 3) * LDB + n] = v.w;
    }
    __syncthreads();
#pragma unroll
    for (int k = 0; k < BK; k++) {
      float4 a4  = *(const float4*)&As[k * LDA + ty * 4];
      float4 b04 = *(const float4*)&Bs[k * LDB + tx * 8];
      float4 b14 = *(const float4*)&Bs[k * LDB + tx * 8 + 4];
      float a[4] = {a4.x, a4.y, a4.z, a4.w};
      float bb[8] = {b04.x, b04.y, b04.z, b04.w, b14.x, b14.y, b14.z, b14.w};
#pragma unroll
      for (int i = 0; i < 4; i++)
#pragma unroll
        for (int j = 0; j < 8; j++) acc[i][j] = fmaf(a[i], bb[j], acc[i][j]);
    }
    __syncthreads();
  }

  // bias + relu, park h tile in LDS
  {
    float4 bb0 = *(const float4*)&bias1[tx * 8];
    float4 bb1 = *(const float4*)&bias1[tx * 8 + 4];
    float bj[8] = {bb0.x, bb0.y, bb0.z, bb0.w, bb1.x, bb1.y, bb1.z, bb1.w};
#pragma unroll
    for (int i = 0; i < 4; i++) {
#pragma unroll
      for (int j = 0; j < 8; j++) acc[i][j] = fmaxf(acc[i][j] + bj[j], 0.f);
      float4 u0 = make_float4(acc[i][0], acc[i][1], acc[i][2], acc[i][3]);
      float4 u1 = make_float4(acc[i][4], acc[i][5], acc[i][6], acc[i][7]);
      *(float4*)&hs[(ty * 4 + i) * LDB + tx * 8]     = u0;
      *(float4*)&hs[(ty * 4 + i) * LDB + tx * 8 + 4] = u1;
    }
  }
  __syncthreads();

  // ---- phase 2: y = h @ W2^T + b2 ----
  float acc2[4][8];
  {
    float4 c0 = *(const float4*)&bias2[tx * 8];
    float4 c1 = *(const float4*)&bias2[tx * 8 + 4];
    float cj[8] = {c0.x, c0.y, c0.z, c0.w, c1.x, c1.y, c1.z, c1.w};
#pragma unroll
    for (int i = 0; i < 4; i++)
#pragma unroll
      for (int j = 0; j < 8; j++) acc2[i][j] = cj[j];
  }
  for (int kk = 0; kk < DD; kk += BK) {
#pragma unroll
    for (int s = 0; s < 4; s++) {
      int f = t + 256 * s;
      int n = f >> 3, kq = f & 7;
      float4 v = *(const float4*)&W2[n * DD + kk + kq * 4];
      Ws[(kq * 4 + 0) * LDB + n] = v.x;
      Ws[(kq * 4 + 1) * LDB + n] = v.y;
      Ws[(kq * 4 + 2) * LDB + n] = v.z;
      Ws[(kq * 4 + 3) * LDB + n] = v.w;
    }
    __syncthreads();
#pragma unroll
    for (int k = 0; k < BK; k++) {
      float a[4];
#pragma unroll
      for (int i = 0; i < 4; i++) a[i] = hs[(ty * 4 + i) * LDB + kk + k];
      float4 b04 = *(const float4*)&Ws[k * LDB + tx * 8];
      float4 b14 = *(const float4*)&Ws[k * LDB + tx * 8 + 4];
      float bb[8] = {b04.x, b04.y, b04.z, b04.w, b14.x, b14.y, b14.z, b14.w};
#pragma unroll
      for (int i = 0; i < 4; i++)
#pragma unroll
        for (int j = 0; j < 8; j++) acc2[i][j] = fmaf(a[i], bb[j], acc2[i][j]);
    }
    __syncthreads();
  }

  // ---- row L2 normalize + store ----
  // lanes with equal (lane>>4) inside a wave share a row group; reduce over tx.
#pragma unroll
  for (int i = 0; i < 4; i++) {
    float s = 0.f;
#pragma unroll
    for (int j = 0; j < 8; j++) s += acc2[i][j] * acc2[i][j];
    s += __shfl_xor(s, 1, 64);
    s += __shfl_xor(s, 2, 64);
    s += __shfl_xor(s, 4, 64);
    s += __shfl_xor(s, 8, 64);
    float rinv = 1.0f / sqrtf(s);
#pragma unroll
    for (int j = 0; j < 8; j++) acc2[i][j] *= rinv;
    float4 u0 = make_float4(acc2[i][0], acc2[i][1], acc2[i][2], acc2[i][3]);
    float4 u1 = make_float4(acc2[i][4], acc2[i][5], acc2[i][6], acc2[i][7]);
    *(float4*)&Y[(m0 + ty * 4 + i) * DD + tx * 8]     = u0;
    *(float4*)&Y[(m0 + ty * 4 + i) * DD + tx * 8 + 4] = u1;
  }
}

// ---------------------------------------------------------------------------
// p_bar[b][d] = mean over l of p[l][b][d]
// ---------------------------------------------------------------------------
__global__ __launch_bounds__(256) void pbar_kernel(const float* __restrict__ p,
                                                   float* __restrict__ pbar)
{
  int idx = blockIdx.x * 256 + threadIdx.x;   // b*DD + d
  float s = 0.f;
#pragma unroll
  for (int l = 0; l < PP; l++) s += p[(size_t)l * B_ * DD + idx];
  pbar[idx] = s * (1.0f / PP);
}

// ---------------------------------------------------------------------------
// Symmetric KL over one D=128 row pair, computed by one 64-lane wave.
// Inputs au*, av* are already scaled by 1/T. Returns sum_i (pu_i-pv_i)*(au_i-av_i)
// (valid in all lanes). The LSE terms cancel exactly in the symmetric sum.
// ---------------------------------------------------------------------------
__device__ __forceinline__ float sym_kl_row(float au0, float au1, float av0, float av1)
{
  float mu = fmaxf(au0, au1);
  float mv = fmaxf(av0, av1);
#pragma unroll
  for (int o = 32; o > 0; o >>= 1) {
    mu = fmaxf(mu, __shfl_xor(mu, o, 64));
    mv = fmaxf(mv, __shfl_xor(mv, o, 64));
  }
  float eu0 = expf(au0 - mu), eu1 = expf(au1 - mu);
  float ev0 = expf(av0 - mv), ev1 = expf(av1 - mv);
  float su = eu0 + eu1, sv = ev0 + ev1;
#pragma unroll
  for (int o = 32; o > 0; o >>= 1) {
    su += __shfl_xor(su, o, 64);
    sv += __shfl_xor(sv, o, 64);
  }
  float ru = 1.0f / su, rv = 1.0f / sv;
  float d0 = au0 - av0, d1 = au1 - av1;
  float part = (eu0 * ru - ev0 * rv) * d0 + (eu1 * ru - ev1 * rv) * d1;
#pragma unroll
  for (int o = 32; o > 0; o >>= 1) part += __shfl_xor(part, o, 64);
  return part;
}

// dil: per row b, sym KL between g[b] and pbar[b]; scale T^2/D = 0.125
__global__ __launch_bounds__(256) void dil_kernel(const float* __restrict__ g,
                                                  const float* __restrict__ pbar,
                                                  float* __restrict__ partial)
{
  __shared__ float wp[4];
  int wid = threadIdx.x >> 6, lane = threadIdx.x & 63;
  int b = blockIdx.x * 4 + wid;
  float2 gv = *(const float2*)&g[(size_t)b * DD + lane * 2];
  float2 pv = *(const float2*)&pbar[(size_t)b * DD + lane * 2];
  float part = sym_kl_row(gv.x * INV_T, gv.y * INV_T, pv.x * INV_T, pv.y * INV_T);
  if (lane == 0) wp[wid] = part * 0.125f;
  __syncthreads();
  if (threadIdx.x == 0) partial[blockIdx.x] = wp[0] + wp[1] + wp[2] + wp[3];
}

// dcl: per row r = l*B + b, sym KL between (g[b]-p[r])^2 and (pbar[b]-p[r])^2
// scale (T^2/D)/P = 1/96
__global__ __launch_bounds__(256) void dcl_kernel(const float* __restrict__ g,
                                                  const float* __restrict__ pbar,
                                                  const float* __restrict__ p,
                                                  float* __restrict__ partial)
{
  __shared__ float wp[4];
  int wid = threadIdx.x >> 6, lane = threadIdx.x & 63;
  int r = blockIdx.x * 4 + wid;
  int b = r & (B_ - 1);
  float2 gv = *(const float2*)&g[(size_t)b * DD + lane * 2];
  float2 bv = *(const float2*)&pbar[(size_t)b * DD + lane * 2];
  float2 pv = *(const float2*)&p[(size_t)r * DD + lane * 2];
  float u0 = (gv.x - pv.x) * (gv.x - pv.x) * INV_T;
  float u1 = (gv.y - pv.y) * (gv.y - pv.y) * INV_T;
  float v0 = (bv.x - pv.x) * (bv.x - pv.x) * INV_T;
  float v1 = (bv.y - pv.y) * (bv.y - pv.y) * INV_T;
  float part = sym_kl_row(u0, u1, v0, v1);
  if (lane == 0) wp[wid] = part * (1.0f / 96.0f);
  __syncthreads();
  if (threadIdx.x == 0) partial[blockIdx.x] = wp[0] + wp[1] + wp[2] + wp[3];
}

// final: out[0] = sum(pdil[0..1023]), out[1] = sum(pdcl[0..12287])
__global__ __launch_bounds__(256) void final_kernel(const float* __restrict__ pd,
                                                    const float* __restrict__ pc,
                                                    float* __restrict__ out)
{
  __shared__ float red[8];
  int t = threadIdx.x;
  float s0 = 0.f, s1 = 0.f;
  for (int i = t; i < 1024; i += 256) s0 += pd[i];
  for (int i = t; i < 12288; i += 256) s1 += pc[i];
#pragma unroll
  for (int o = 32; o > 0; o >>= 1) {
    s0 += __shfl_xor(s0, o, 64);
    s1 += __shfl_xor(s1, o, 64);
  }
  int wid = t >> 6, lane = t & 63;
  if (lane == 0) { red[wid] = s0; red[4 + wid] = s1; }
  __syncthreads();
  if (t == 0) out[0] = red[0] + red[1] + red[2] + red[3];
  if (t == 1) out[1] = red[4] + red[5] + red[6] + red[7];
}

extern "C" void kernel_launch(void* const* d_in, const int* in_sizes, int n_in,
                              void* d_out, int out_size, void* d_ws, size_t ws_size,
                              hipStream_t stream)
{
  const float* ebg = (const float*)d_in[0];
  const float* ebp = (const float*)d_in[1];
  // d_in[2] = labelsg (unused by the reference)
  const float* gw1 = (const float*)d_in[3];
  const float* gb1 = (const float*)d_in[4];
  const float* gw2 = (const float*)d_in[5];
  const float* gb2 = (const float*)d_in[6];
  const float* pw1 = (const float*)d_in[7];
  const float* pb1 = (const float*)d_in[8];
  const float* pw2 = (const float*)d_in[9];
  const float* pb2 = (const float*)d_in[10];
  float* out = (float*)d_out;

  float* ws   = (float*)d_ws;
  float* g    = ws;                        // 4096*128
  float* p    = g + (size_t)B_ * DD;       // 49152*128
  float* pbar = p + (size_t)PP * B_ * DD;  // 4096*128
  float* pdil = pbar + (size_t)B_ * DD;    // 1024
  float* pdcl = pdil + 1024;               // 12288

  embed_kernel<<<B_ / TM, 256, 0, stream>>>(ebg, gw1, gb1, gw2, gb2, g);
  embed_kernel<<<PP * B_ / TM, 256, 0, stream>>>(ebp, pw1, pb1, pw2, pb2, p);
  pbar_kernel<<<B_ * DD / 256, 256, 0, stream>>>(p, pbar);
  dil_kernel<<<B_ / 4, 256, 0, stream>>>(g, pbar, pdil);
  dcl_kernel<<<PP * B_ / 4, 256, 0, stream>>>(g, pbar, p, pdcl);
  final_kernel<<<1, 256, 0, stream>>>(pdil, pdcl, out);
}

// Round 2
// 374.090 us; speedup vs baseline: 1.1207x; 1.1207x over previous
//
#include <hip/hip_runtime.h>
#include <math.h>

#define B_    4096
#define DIN   640
#define DD    128
#define PP    12
#define TM    64
#define BK1   32
#define NT1   (DIN / BK1)   // 20
#define BK2   16
#define NT2   (DD / BK2)    // 8
#define LDA   68
#define INV_T 0.25f

// ---------------------------------------------------------------------------
// Batched transpose: builds W1T (640x128) and W2T (128x128) for both weight
// sets. in[R][C] -> out[C][R], 32x32 LDS tiles.
// ---------------------------------------------------------------------------
__global__ __launch_bounds__(256) void transpose_kernel(
    const float* __restrict__ gw1, const float* __restrict__ pw1,
    const float* __restrict__ gw2, const float* __restrict__ pw2,
    float* __restrict__ w1tg, float* __restrict__ w1tp,
    float* __restrict__ w2tg, float* __restrict__ w2tp)
{
  __shared__ float tile[32][33];
  int bid = blockIdx.x;
  const float* in; float* out; int R, C, tb;
  if (bid < 80)       { in = gw1; out = w1tg; R = 128; C = 640; tb = bid; }
  else if (bid < 160) { in = pw1; out = w1tp; R = 128; C = 640; tb = bid - 80; }
  else if (bid < 176) { in = gw2; out = w2tg; R = 128; C = 128; tb = bid - 160; }
  else                { in = pw2; out = w2tp; R = 128; C = 128; tb = bid - 176; }
  int ctiles = C >> 5;
  int bx = tb % ctiles, by = tb / ctiles;
  int tx = threadIdx.x & 31, ty = threadIdx.x >> 5;   // 32 x 8
#pragma unroll
  for (int r = 0; r < 4; r++)
    tile[ty + r * 8][tx] = in[(by * 32 + ty + r * 8) * C + bx * 32 + tx];
  __syncthreads();
#pragma unroll
  for (int r = 0; r < 4; r++)
    out[(bx * 32 + ty + r * 8) * R + by * 32 + tx] = tile[tx][ty + r * 8];
}

// ---------------------------------------------------------------------------
// Fused embed for BOTH streams: blocks 0..63 -> glo(ebg), 64..831 -> pat(ebp).
// Y = normalize_rows( relu(X @ W1^T + b1) @ W2^T + b2 )
// 64x128 tile / 256 threads / 4x8 microtile, columns split {tx*4, 64+tx*4}.
// LDS exactly 40 KiB: hs[64][128] (As[32][68]+Bs[32][128] aliased) + Ws[16][128].
// ---------------------------------------------------------------------------
__global__ __launch_bounds__(256) void embed_kernel(
    const float* __restrict__ ebg, const float* __restrict__ ebp,
    const float* __restrict__ w1tg, const float* __restrict__ b1g,
    const float* __restrict__ w2tg, const float* __restrict__ b2g,
    const float* __restrict__ w1tp, const float* __restrict__ b1p,
    const float* __restrict__ w2tp, const float* __restrict__ b2p,
    float* __restrict__ outg, float* __restrict__ outp)
{
  __shared__ float smem[10240];        // 40960 B
  float* hs = smem;                    // [64][128]
  float* As = smem;                    // [32][68]  (aliases hs)
  float* Bs = smem + BK1 * LDA;        // [32][128] (aliases hs, 2176..6272)
  float* Ws = smem + TM * DD;          // [16][128] (8192..10240)

  const int t  = threadIdx.x;
  const int tx = t & 15;
  const int ty = t >> 4;

  const float *X, *W1T, *B1, *W2T, *B2;
  float* Y;
  long m0;
  {
    int bid = blockIdx.x;
    if (bid < 64) { X = ebg; W1T = w1tg; B1 = b1g; W2T = w2tg; B2 = b2g; Y = outg; m0 = (long)bid * TM; }
    else          { X = ebp; W1T = w1tp; B1 = b1p; W2T = w2tp; B2 = b2p; Y = outp; m0 = (long)(bid - 64) * TM; }
  }

  // staging coords
  const int arow = t & 63;             // A: row (same both stages; 256 % 64 == 0)
  const int akq0 = t >> 6;             // A: k-quad stage0 (0..3); stage1 = +4
  const float* Xr = X + (m0 + arow) * DIN;
  const int bk = t >> 5;               // B/W: k-row within tile (0..7)
  const int bc = t & 31;               // B/W: float4 column index

  float acc[4][8];
#pragma unroll
  for (int i = 0; i < 4; i++)
#pragma unroll
    for (int j = 0; j < 8; j++) acc[i][j] = 0.f;

  // ---- phase 1: h = relu(X @ W1^T + b1), pipelined ----
  float4 pa0, pa1, pb0, pb1, pb2, pb3;
  pa0 = *(const float4*)(Xr + akq0 * 4);
  pa1 = *(const float4*)(Xr + (akq0 + 4) * 4);
  pb0 = *(const float4*)(W1T + (bk + 0)  * DD + bc * 4);
  pb1 = *(const float4*)(W1T + (bk + 8)  * DD + bc * 4);
  pb2 = *(const float4*)(W1T + (bk + 16) * DD + bc * 4);
  pb3 = *(const float4*)(W1T + (bk + 24) * DD + bc * 4);

  for (int kt = 0; kt < NT1; kt++) {
    __syncthreads();
    // A: lanes row-consecutive -> conflict-free b32 stores
    As[((akq0    ) * 4 + 0) * LDA + arow] = pa0.x;
    As[((akq0    ) * 4 + 1) * LDA + arow] = pa0.y;
    As[((akq0    ) * 4 + 2) * LDA + arow] = pa0.z;
    As[((akq0    ) * 4 + 3) * LDA + arow] = pa0.w;
    As[((akq0 + 4) * 4 + 0) * LDA + arow] = pa1.x;
    As[((akq0 + 4) * 4 + 1) * LDA + arow] = pa1.y;
    As[((akq0 + 4) * 4 + 2) * LDA + arow] = pa1.z;
    As[((akq0 + 4) * 4 + 3) * LDA + arow] = pa1.w;
    // B: consecutive-lane float4 stores -> conflict-free
    *(float4*)(Bs + (bk + 0)  * DD + bc * 4) = pb0;
    *(float4*)(Bs + (bk + 8)  * DD + bc * 4) = pb1;
    *(float4*)(Bs + (bk + 16) * DD + bc * 4) = pb2;
    *(float4*)(Bs + (bk + 24) * DD + bc * 4) = pb3;
    __syncthreads();
    if (kt + 1 < NT1) {       // prefetch next tile into registers
      int k0 = (kt + 1) * BK1;
      pa0 = *(const float4*)(Xr + k0 + akq0 * 4);
      pa1 = *(const float4*)(Xr + k0 + (akq0 + 4) * 4);
      pb0 = *(const float4*)(W1T + (k0 + bk + 0)  * DD + bc * 4);
      pb1 = *(const float4*)(W1T + (k0 + bk + 8)  * DD + bc * 4);
      pb2 = *(const float4*)(W1T + (k0 + bk + 16) * DD + bc * 4);
      pb3 = *(const float4*)(W1T + (k0 + bk + 24) * DD + bc * 4);
    }
#pragma unroll
    for (int k = 0; k < BK1; k++) {
      float4 a4  = *(const float4*)(As + k * LDA + ty * 4);
      float4 b04 = *(const float4*)(Bs + k * DD + tx * 4);
      float4 b14 = *(const float4*)(Bs + k * DD + 64 + tx * 4);
      float a[4]  = {a4.x, a4.y, a4.z, a4.w};
      float bb[8] = {b04.x, b04.y, b04.z, b04.w, b14.x, b14.y, b14.z, b14.w};
#pragma unroll
      for (int i = 0; i < 4; i++)
#pragma unroll
        for (int j = 0; j < 8; j++) acc[i][j] = fmaf(a[i], bb[j], acc[i][j]);
    }
  }
  __syncthreads();   // As/Bs dead; safe to overwrite via hs

  // bias1 + relu -> hs
  {
    float4 q0 = *(const float4*)(B1 + tx * 4);
    float4 q1 = *(const float4*)(B1 + 64 + tx * 4);
    float bj[8] = {q0.x, q0.y, q0.z, q0.w, q1.x, q1.y, q1.z, q1.w};
#pragma unroll
    for (int i = 0; i < 4; i++) {
#pragma unroll
      for (int j = 0; j < 8; j++) acc[i][j] = fmaxf(acc[i][j] + bj[j], 0.f);
      *(float4*)(hs + (ty * 4 + i) * DD + tx * 4)      = make_float4(acc[i][0], acc[i][1], acc[i][2], acc[i][3]);
      *(float4*)(hs + (ty * 4 + i) * DD + 64 + tx * 4) = make_float4(acc[i][4], acc[i][5], acc[i][6], acc[i][7]);
    }
  }

  // ---- phase 2: y = h @ W2^T + b2, pipelined ----
  float acc2[4][8];
  {
    float4 q0 = *(const float4*)(B2 + tx * 4);
    float4 q1 = *(const float4*)(B2 + 64 + tx * 4);
    float cj[8] = {q0.x, q0.y, q0.z, q0.w, q1.x, q1.y, q1.z, q1.w};
#pragma unroll
    for (int i = 0; i < 4; i++)
#pragma unroll
      for (int j = 0; j < 8; j++) acc2[i][j] = cj[j];
  }
  float4 pw0 = *(const float4*)(W2T + (bk + 0) * DD + bc * 4);
  float4 pw1 = *(const float4*)(W2T + (bk + 8) * DD + bc * 4);

  for (int kt = 0; kt < NT2; kt++) {
    __syncthreads();   // (kt=0: also fences h-writes above)
    *(float4*)(Ws + (bk + 0) * DD + bc * 4) = pw0;
    *(float4*)(Ws + (bk + 8) * DD + bc * 4) = pw1;
    __syncthreads();
    if (kt + 1 < NT2) {
      int kk = (kt + 1) * BK2;
      pw0 = *(const float4*)(W2T + (kk + bk + 0) * DD + bc * 4);
      pw1 = *(const float4*)(W2T + (kk + bk + 8) * DD + bc * 4);
    }
    int kkb = kt * BK2;
#pragma unroll
    for (int k4 = 0; k4 < 4; k4++) {
      float av[4][4];
#pragma unroll
      for (int i = 0; i < 4; i++) {
        float4 a4 = *(const float4*)(hs + (ty * 4 + i) * DD + kkb + k4 * 4);
        av[i][0] = a4.x; av[i][1] = a4.y; av[i][2] = a4.z; av[i][3] = a4.w;
      }
#pragma unroll
      for (int e = 0; e < 4; e++) {
        int k = k4 * 4 + e;
        float4 b04 = *(const float4*)(Ws + k * DD + tx * 4);
        float4 b14 = *(const float4*)(Ws + k * DD + 64 + tx * 4);
        float bb[8] = {b04.x, b04.y, b04.z, b04.w, b14.x, b14.y, b14.z, b14.w};
#pragma unroll
        for (int i = 0; i < 4; i++)
#pragma unroll
          for (int j = 0; j < 8; j++) acc2[i][j] = fmaf(av[i][e], bb[j], acc2[i][j]);
      }
    }
  }

  // ---- L2 normalize + store ----
#pragma unroll
  for (int i = 0; i < 4; i++) {
    float s = 0.f;
#pragma unroll
    for (int j = 0; j < 8; j++) s += acc2[i][j] * acc2[i][j];
    s += __shfl_xor(s, 1, 64);
    s += __shfl_xor(s, 2, 64);
    s += __shfl_xor(s, 4, 64);
    s += __shfl_xor(s, 8, 64);
    float rinv = 1.0f / sqrtf(s);
#pragma unroll
    for (int j = 0; j < 8; j++) acc2[i][j] *= rinv;
    long row = m0 + ty * 4 + i;
    *(float4*)(Y + row * DD + tx * 4)      = make_float4(acc2[i][0], acc2[i][1], acc2[i][2], acc2[i][3]);
    *(float4*)(Y + row * DD + 64 + tx * 4) = make_float4(acc2[i][4], acc2[i][5], acc2[i][6], acc2[i][7]);
  }
}

// ---------------------------------------------------------------------------
// p_bar[b][d] = mean over l of p[l][b][d]
// ---------------------------------------------------------------------------
__global__ __launch_bounds__(256) void pbar_kernel(const float* __restrict__ p,
                                                   float* __restrict__ pbar)
{
  int idx = blockIdx.x * 256 + threadIdx.x;
  float s = 0.f;
#pragma unroll
  for (int l = 0; l < PP; l++) s += p[(size_t)l * B_ * DD + idx];
  pbar[idx] = s * (1.0f / PP);
}

// ---------------------------------------------------------------------------
// Symmetric KL of one D=128 row pair per 64-lane wave; inputs pre-scaled 1/T.
// sym = sum_i (pu_i - pv_i)*(au_i - av_i)  (LSE terms cancel exactly).
// ---------------------------------------------------------------------------
__device__ __forceinline__ float sym_kl_row(float au0, float au1, float av0, float av1)
{
  float mu = fmaxf(au0, au1);
  float mv = fmaxf(av0, av1);
#pragma unroll
  for (int o = 32; o > 0; o >>= 1) {
    mu = fmaxf(mu, __shfl_xor(mu, o, 64));
    mv = fmaxf(mv, __shfl_xor(mv, o, 64));
  }
  float eu0 = expf(au0 - mu), eu1 = expf(au1 - mu);
  float ev0 = expf(av0 - mv), ev1 = expf(av1 - mv);
  float su = eu0 + eu1, sv = ev0 + ev1;
#pragma unroll
  for (int o = 32; o > 0; o >>= 1) {
    su += __shfl_xor(su, o, 64);
    sv += __shfl_xor(sv, o, 64);
  }
  float ru = 1.0f / su, rv = 1.0f / sv;
  float d0 = au0 - av0, d1 = au1 - av1;
  float part = (eu0 * ru - ev0 * rv) * d0 + (eu1 * ru - ev1 * rv) * d1;
#pragma unroll
  for (int o = 32; o > 0; o >>= 1) part += __shfl_xor(part, o, 64);
  return part;
}

// Merged dil (blocks 0..1023) + dcl (blocks 1024..13311)
__global__ __launch_bounds__(256) void kl_kernel(const float* __restrict__ g,
                                                 const float* __restrict__ pbar,
                                                 const float* __restrict__ p,
                                                 float* __restrict__ partial)
{
  __shared__ float wp[4];
  int bid = blockIdx.x;
  int wid = threadIdx.x >> 6, lane = threadIdx.x & 63;
  float contrib;
  if (bid < B_ / 4) {
    int b = bid * 4 + wid;
    float2 gv = *(const float2*)&g[(size_t)b * DD + lane * 2];
    float2 pv = *(const float2*)&pbar[(size_t)b * DD + lane * 2];
    contrib = sym_kl_row(gv.x * INV_T, gv.y * INV_T, pv.x * INV_T, pv.y * INV_T) * 0.125f;
  } else {
    int r = (bid - B_ / 4) * 4 + wid;
    int b = r & (B_ - 1);
    float2 gv = *(const float2*)&g[(size_t)b * DD + lane * 2];
    float2 bv = *(const float2*)&pbar[(size_t)b * DD + lane * 2];
    float2 pv = *(const float2*)&p[(size_t)r * DD + lane * 2];
    float u0 = (gv.x - pv.x) * (gv.x - pv.x) * INV_T;
    float u1 = (gv.y - pv.y) * (gv.y - pv.y) * INV_T;
    float v0 = (bv.x - pv.x) * (bv.x - pv.x) * INV_T;
    float v1 = (bv.y - pv.y) * (bv.y - pv.y) * INV_T;
    contrib = sym_kl_row(u0, u1, v0, v1) * (1.0f / 96.0f);
  }
  if (lane == 0) wp[wid] = contrib;
  __syncthreads();
  if (threadIdx.x == 0) partial[bid] = wp[0] + wp[1] + wp[2] + wp[3];
}

// out[0] = sum partial[0..1023], out[1] = sum partial[1024..13311]
__global__ __launch_bounds__(256) void final_kernel(const float* __restrict__ partial,
                                                    float* __restrict__ out)
{
  __shared__ float red[8];
  int t = threadIdx.x;
  float s0 = 0.f, s1 = 0.f;
  for (int i = t; i < 1024; i += 256) s0 += partial[i];
  for (int i = 1024 + t; i < 13312; i += 256) s1 += partial[i];
#pragma unroll
  for (int o = 32; o > 0; o >>= 1) {
    s0 += __shfl_xor(s0, o, 64);
    s1 += __shfl_xor(s1, o, 64);
  }
  int wid = t >> 6, lane = t & 63;
  if (lane == 0) { red[wid] = s0; red[4 + wid] = s1; }
  __syncthreads();
  if (t == 0) out[0] = red[0] + red[1] + red[2] + red[3];
  if (t == 1) out[1] = red[4] + red[5] + red[6] + red[7];
}

extern "C" void kernel_launch(void* const* d_in, const int* in_sizes, int n_in,
                              void* d_out, int out_size, void* d_ws, size_t ws_size,
                              hipStream_t stream)
{
  const float* ebg = (const float*)d_in[0];
  const float* ebp = (const float*)d_in[1];
  const float* gw1 = (const float*)d_in[3];
  const float* gb1 = (const float*)d_in[4];
  const float* gw2 = (const float*)d_in[5];
  const float* gb2 = (const float*)d_in[6];
  const float* pw1 = (const float*)d_in[7];
  const float* pb1 = (const float*)d_in[8];
  const float* pw2 = (const float*)d_in[9];
  const float* pb2 = (const float*)d_in[10];
  float* out = (float*)d_out;

  float* ws      = (float*)d_ws;
  float* g       = ws;                           // 524288
  float* p       = g + (size_t)B_ * DD;          // 6291456
  float* pbar    = p + (size_t)PP * B_ * DD;     // 524288
  float* partial = pbar + (size_t)B_ * DD;       // 13312
  float* w1tg    = partial + 13312;              // 81920
  float* w1tp    = w1tg + DIN * DD;              // 81920
  float* w2tg    = w1tp + DIN * DD;              // 16384
  float* w2tp    = w2tg + DD * DD;               // 16384

  transpose_kernel<<<192, 256, 0, stream>>>(gw1, pw1, gw2, pw2, w1tg, w1tp, w2tg, w2tp);
  embed_kernel<<<64 + PP * B_ / TM, 256, 0, stream>>>(
      ebg, ebp, w1tg, gb1, w2tg, gb2, w1tp, pb1, w2tp, pb2, g, p);
  pbar_kernel<<<B_ * DD / 256, 256, 0, stream>>>(p, pbar);
  kl_kernel<<<(B_ / 4) + (PP * B_ / 4), 256, 0, stream>>>(g, pbar, p, partial);
  final_kernel<<<1, 256, 0, stream>>>(partial, out);
}